// Round 2
// baseline (155.411 us; speedup 1.0000x reference)
//
#include <hip/hip_runtime.h>
#include <hip/hip_bf16.h>

namespace {

constexpr int kB  = 16;    // batches
constexpr int kP  = 8;     // pieces
constexpr int kNT = 512;   // time steps (incl. t=0)
constexpr int kNX = 2048;  // cells
constexpr int kT  = 512;   // threads per block
constexpr int kC  = kNX / kT;  // 4 cells per thread

// Godunov flux for f(u) = u(1-u); fL/fR precomputed f(uL), f(uR)
__device__ __forceinline__ float gflux(float uL, float uR, float fL, float fR) {
    float fmn = fminf(fL, fR);
    float fmx = (uL >= 0.5f && uR <= 0.5f) ? 0.25f : fmaxf(fL, fR);
    return (uL <= uR) ? fmn : fmx;
}

__global__ __launch_bounds__(kT)
void godunov_kernel(const float* __restrict__ xs,   // (B, P+1)
                    const float* __restrict__ ks,   // (B, P)
                    const int*   __restrict__ pm,   // (B, P)
                    const float* __restrict__ dxp,  // (B,)
                    const float* __restrict__ dtp,  // (B,)
                    float* __restrict__ out)        // (B, 1, NT, NX) fp32
{
    // Double-buffered halo arrays: only per-thread boundary cells cross LDS.
    __shared__ float sbL[2][kT + 1];  // sbL[buf][t] = leftmost cell of thread t; [kT] = gR
    __shared__ float sbR[2][kT + 1];  // sbR[buf][t+1] = rightmost cell of thread t; [0] = gL

    const int b = blockIdx.x;
    const int t = threadIdx.x;
    const float dxv = dxp[0];
    const float lam = dtp[0] / dxv;

    // ---- initial condition (piecewise-constant from xs/ks) ----
    int npieces = 0;
    float bnds[kP];
#pragma unroll
    for (int j = 0; j < kP; ++j) {
        int m = pm[b * kP + j];
        npieces += m;
        bnds[j] = m ? xs[b * (kP + 1) + j + 1] : __builtin_inff();
    }
    const int cap = npieces - 1;

    float u[kC];
#pragma unroll
    for (int c = 0; c < kC; ++c) {
        int i = t * kC + c;
        float xc = ((float)i + 0.5f) * dxv;
        int idx = 0;
#pragma unroll
        for (int j = 0; j < kP; ++j) idx += (xc >= bnds[j]) ? 1 : 0;
        idx = min(idx, cap);
        u[c] = ks[b * kP + idx];
    }

    // Ghost cells: gL = ic[0], gR = ic[NX-1]; constant for all steps, both buffers.
    if (t == 0) {
        sbR[0][0] = u[0];
        sbR[1][0] = u[0];
    }
    if (t == kT - 1) {
        sbL[0][kT] = u[kC - 1];
        sbL[1][kT] = u[kC - 1];
    }
    sbL[0][t]     = u[0];
    sbR[0][t + 1] = u[kC - 1];

    // Output row pointer for this thread (advance by one row per step).
    float4* orow = reinterpret_cast<float4*>(out + ((size_t)b * kNT) * kNX + (size_t)t * kC);
    const int rowStride = kNX / kC;  // in float4 units

    // row 0 = initial condition
    {
        float4 o = make_float4(u[0], u[1], u[2], u[3]);
        orow[0] = o;
        orow += rowStride;
    }

    __syncthreads();

    int cur = 0;
    for (int s = 1; s < kNT; ++s) {
        float um = sbR[cur][t];      // u[i0-1] (or gL)
        float up = sbL[cur][t + 1];  // u[i0+kC] (or gR)

        float f[kC];
#pragma unroll
        for (int c = 0; c < kC; ++c) f[c] = u[c] * (1.0f - u[c]);
        float fm = um * (1.0f - um);
        float fp = up * (1.0f - up);

        float F[kC + 1];
        F[0] = gflux(um, u[0], fm, f[0]);
#pragma unroll
        for (int c = 1; c < kC; ++c) F[c] = gflux(u[c - 1], u[c], f[c - 1], f[c]);
        F[kC] = gflux(u[kC - 1], up, f[kC - 1], fp);

#pragma unroll
        for (int c = 0; c < kC; ++c) u[c] = u[c] - lam * (F[c + 1] - F[c]);

        int nxt = cur ^ 1;
        sbL[nxt][t]     = u[0];
        sbR[nxt][t + 1] = u[kC - 1];

        float4 o = make_float4(u[0], u[1], u[2], u[3]);
        *orow = o;
        orow += rowStride;

        cur = nxt;
        __syncthreads();
    }
}

}  // namespace

extern "C" void kernel_launch(void* const* d_in, const int* in_sizes, int n_in,
                              void* d_out, int out_size, void* d_ws, size_t ws_size,
                              hipStream_t stream) {
    const float* xs  = (const float*)d_in[0];
    const float* ks  = (const float*)d_in[1];
    const int*   pm  = (const int*)d_in[2];
    const float* dxv = (const float*)d_in[3];
    const float* dtv = (const float*)d_in[4];
    // d_in[5] = t_coords: only carries the (NT, NX) shape; values unused.
    float* out = (float*)d_out;

    hipLaunchKernelGGL(godunov_kernel, dim3(kB), dim3(kT), 0, stream,
                       xs, ks, pm, dxv, dtv, out);
}